// Round 3
// baseline (193.134 us; speedup 1.0000x reference)
//
#include <hip/hip_runtime.h>
#include <hip/hip_bf16.h>

// Problem constants: B=2, T=2048, D=1024, H=16, DK=64
constexpr int Bc = 2;
constexpr int Tc = 2048;
constexpr int Mc = Bc * Tc;  // 4096
constexpr float CfQ = 0.18033688011112042f;  // (1/sqrt(64)) * log2(e)

typedef __attribute__((ext_vector_type(8))) __bf16 bf16x8;
typedef __attribute__((ext_vector_type(4))) __bf16 bf16x4;
typedef __attribute__((ext_vector_type(4))) float floatx4;
typedef __attribute__((ext_vector_type(16))) float f32x16;
typedef __attribute__((ext_vector_type(4))) unsigned int uint4v;

__device__ __forceinline__ void gl_lds16(const void* g, void* l) {
    __builtin_amdgcn_global_load_lds(
        (const __attribute__((address_space(1))) void*)g,
        (__attribute__((address_space(3))) void*)l, 16, 0, 0);
}

// pack two f32 -> one dword of 2 bf16 (compiler emits v_cvt_pk_bf16_f32)
__device__ __forceinline__ unsigned int pkbf(float x, float y) {
    union { __bf16 h[2]; unsigned int u; } z;
    z.h[0] = (__bf16)x; z.h[1] = (__bf16)y;
    return z.u;
}

// ---------------------------------------------------------------------------
// Prep: z<4 -> weight transpose+convert; z>=4 -> x fp32->bf16 convert slices.
// ---------------------------------------------------------------------------
__global__ __launch_bounds__(256) void prep_all(const float* __restrict__ x,
                                                const float* __restrict__ Wq,
                                                const float* __restrict__ Wk,
                                                const float* __restrict__ Wv,
                                                const float* __restrict__ Wo,
                                                __bf16* __restrict__ xb,
                                                __bf16* __restrict__ Wqkv,
                                                __bf16* __restrict__ Wot) {
    const int z = blockIdx.z;
    const int tid = threadIdx.x;
    if (z >= 4) {
        const int lb = blockIdx.y * 16 + blockIdx.x;
        const size_t base = ((size_t)(z - 4) * 256 + lb) * 4096;
#pragma unroll
        for (int it = 0; it < 4; ++it) {
            const size_t i = base + (size_t)(it * 256 + tid) * 4;
            const float4 v = *(const float4*)(x + i);
            bf16x4 r;
            r[0] = (__bf16)v.x; r[1] = (__bf16)v.y;
            r[2] = (__bf16)v.z; r[3] = (__bf16)v.w;
            *(bf16x4*)(xb + i) = r;
        }
        return;
    }
    __shared__ float t[64][65];
    const float* W = (z == 0) ? Wq : (z == 1) ? Wk : (z == 2) ? Wv : Wo;
    __bf16* Wt = (z < 3) ? Wqkv + (size_t)z * 1024 * 1024 : Wot;
    const int k0 = blockIdx.y * 64, n0 = blockIdx.x * 64;
    const int c = tid & 63, r0 = tid >> 6;
#pragma unroll
    for (int i = 0; i < 16; ++i)
        t[r0 + i * 4][c] = W[(size_t)(k0 + r0 + i * 4) * 1024 + n0 + c];
    __syncthreads();
#pragma unroll
    for (int i = 0; i < 16; ++i) {
        const int r = r0 + i * 4;
        Wt[(size_t)(n0 + r) * 1024 + k0 + c] = (__bf16)t[c][r];
    }
}

// ---------------------------------------------------------------------------
// bf16 MFMA GEMM, BK=64 (32 MFMA per barrier): C = A @ Bt^T + bias.
// 128xTN tile, 256 threads = 4 waves. LDS tiles XOR-swizzled in 16B chunks
// (phys chunk p of row r holds logical chunk p^(r&7)) -> conflict-free
// capacity-even frag reads with gl_lds-compatible staging.
// FUSE_VT (QKV gemm): cols <1024 (Q) pre-scaled by CfQ; cols >=2048 (V)
// stream into Vt[bh][d][t] (PLAIN layout: 32x32x16 attention A-frags are
// straight 16B slices along t).
// ---------------------------------------------------------------------------
template <int TN, bool BF16_OUT, bool FUSE_VT>
__global__ __launch_bounds__(256) void gemm_bt(const __bf16* __restrict__ A,
                                               const __bf16* __restrict__ Bt,
                                               const float* __restrict__ b0,
                                               const float* __restrict__ b1,
                                               const float* __restrict__ b2,
                                               void* __restrict__ Cv,
                                               __bf16* __restrict__ Vt,
                                               int K, int ldc) {
    constexpr int NI = TN / 32;
    __shared__ __bf16 As[128 * 64];
    __shared__ __bf16 Bs[TN * 64];
    const int tid = threadIdx.x, lane = tid & 63, wave = tid >> 6;
    const int wm = wave & 1, wn = wave >> 1;
    const int bm = blockIdx.y * 128, bn = blockIdx.x * TN;
    const __bf16* Ab = A + (size_t)bm * K;
    const __bf16* Bb = Bt + (size_t)bn * K;
    const int quad = lane >> 4, tm = lane & 15;
    const int tsw = tm & 7;

    floatx4 acc[4][NI] = {};

    for (int k0 = 0; k0 < K; k0 += 64) {
#pragma unroll
        for (int i = 0; i < 4; ++i) {
            const int s = i * 256 + tid;
            const int row = s >> 3;
            const int lc = (s & 7) ^ (row & 7);
            gl_lds16(Ab + (size_t)row * K + k0 + lc * 8, As + s * 8);
        }
#pragma unroll
        for (int i = 0; i < TN / 32; ++i) {
            const int s = i * 256 + tid;
            const int row = s >> 3;
            const int lc = (s & 7) ^ (row & 7);
            gl_lds16(Bb + (size_t)row * K + k0 + lc * 8, Bs + s * 8);
        }
        __syncthreads();
        bf16x8 af[4][2], bfv[NI][2];
#pragma unroll
        for (int mi = 0; mi < 4; ++mi) {
            const int row = (wm * 64 + mi * 16 + tm) * 64;
#pragma unroll
            for (int ks = 0; ks < 2; ++ks)
                af[mi][ks] = *(const bf16x8*)(As + row + ((ks * 4 + quad) ^ tsw) * 8);
        }
#pragma unroll
        for (int ni = 0; ni < NI; ++ni) {
            const int row = (wn * (TN / 2) + ni * 16 + tm) * 64;
#pragma unroll
            for (int ks = 0; ks < 2; ++ks)
                bfv[ni][ks] = *(const bf16x8*)(Bs + row + ((ks * 4 + quad) ^ tsw) * 8);
        }
#pragma unroll
        for (int ks = 0; ks < 2; ++ks)
#pragma unroll
            for (int mi = 0; mi < 4; ++mi)
#pragma unroll
                for (int ni = 0; ni < NI; ++ni)
                    acc[mi][ni] = __builtin_amdgcn_mfma_f32_16x16x32_bf16(
                        af[mi][ks], bfv[ni][ks], acc[mi][ni], 0, 0, 0);
        __syncthreads();
    }

#pragma unroll
    for (int ni = 0; ni < NI; ++ni) {
        const int gc = bn + wn * (TN / 2) + ni * 16 + tm;
        const float bias = (gc < 1024) ? b0[gc]
                         : (gc < 2048) ? b1[gc - 1024]
                                       : b2[gc - 2048];
        const float scale = (FUSE_VT && gc < 1024) ? CfQ : 1.0f;
#pragma unroll
        for (int mi = 0; mi < 4; ++mi) {
            const int gr0 = bm + wm * 64 + mi * 16 + quad * 4;
            if (FUSE_VT && gc >= 2048) {
                bf16x4 pv;
#pragma unroll
                for (int r = 0; r < 4; ++r) pv[r] = (__bf16)(acc[mi][ni][r] + bias);
                const int bb = gr0 >> 11, tloc = gr0 & 2047;
                const int hh = (gc - 2048) >> 6, dd = gc & 63;
                *(bf16x4*)(Vt + ((size_t)(bb * 16 + hh) * 64 + dd) * 2048 + tloc) = pv;
            } else if (BF16_OUT) {
#pragma unroll
                for (int r = 0; r < 4; ++r)
                    ((__bf16*)Cv)[(size_t)(gr0 + r) * ldc + gc] =
                        (__bf16)((acc[mi][ni][r] + bias) * scale);
            } else {
#pragma unroll
                for (int r = 0; r < 4; ++r)
                    ((float*)Cv)[(size_t)(gr0 + r) * ldc + gc] =
                        acc[mi][ni][r] + bias;
            }
        }
    }
}

// ---------------------------------------------------------------------------
// MFMA flash attention (causal), S^T formulation, 32x32x16 MFMA.
// Grid: 256 blocks x 512 thr (8 waves), 1 block/CU, XCD-bh-clustered.
// q-tile = 128 rows; 2 groups of 4 waves (each wave 32 q-cols) split kt
// even/odd; pairing (ip, 15-ip) -> uniform 17 pair-iterations per block.
// Per wave-kt: QK^T = 8 MFMA (2 ktile x 4 dk-chunk), PV = 8 MFMA
// (2 dtile x 4 t-chunk); 16 FLOP/LDS-byte (2x the 16x16 shape).
// P^T B-frag built in-register: cvt-pk pairs + __shfl_xor(.,32) cross-half
// exchange (C-layout rows 0-3,8-11 live in lo-half, 4-7,12-15 in hi-half).
// V layout plain [bh][d][t] -> A-frag = single swizzled b128 read.
// Counted-vmcnt pipeline (depth 2 pairs), setprio around MFMA clusters.
// ---------------------------------------------------------------------------
__global__ __launch_bounds__(512, 2) void attn_mfma(const __bf16* __restrict__ QK,
                                                    const __bf16* __restrict__ Vt,
                                                    __bf16* __restrict__ ctx) {
    constexpr float NEG = -1e30f;

    __shared__ __bf16 Ks[2][2][64 * 64];   // [dbuf][group][tile]
    __shared__ __bf16 Vts[2][2][64 * 64];

    const int tid = threadIdx.x, lane = tid & 63, w = tid >> 6;
    const int g = w >> 2, ws = w & 3;      // k-group, wave-in-group (q sub-block)
    const int col = lane & 31, hi = lane >> 5;
    // XCD-clustered remap: 256 blocks, xcd = n&7 hosts bh {4x..4x+3}
    const int n = blockIdx.x;
    const int bh = (n & 7) * 4 + ((n >> 3) & 3);
    const int ip = n >> 5;                 // pair index: q-tiles (ip, 15-ip)
    const int b = bh >> 4, h = bh & 15;

    const __bf16* Qb = QK + (size_t)(b * Tc) * 2048 + h * 64;
    const __bf16* Kb = Qb + 1024;
    const __bf16* Vtb = Vt + (size_t)bh * 64 * 2048;

    // --- frag LDS offsets: off[i][c] for row i*32+col, 16B chunk c*2+hi,
    //     phys chunk = logical ^ (row&7); (i*32+col)&7 == col&7 ---
    const int sw = col & 7;
    int off[2][4];
#pragma unroll
    for (int i = 0; i < 2; ++i)
#pragma unroll
        for (int cc = 0; cc < 4; ++cc)
            off[i][cc] = (i * 32 + col) * 64 + (((cc * 2 + hi) ^ sw) * 8);

    // --- staging addresses: 512 threads, 1 chunk (16B) per tile per thread ---
    const int srow = tid >> 3;                       // 0..63
    const int slc = (tid & 7) ^ (srow & 7);          // swizzled chunk
    const __bf16* kgB = Kb + (size_t)srow * 2048 + slc * 8;   // K tile t: +t*64*2048
    const __bf16* vgB = Vtb + (size_t)srow * 2048 + slc * 8;  // V tile t: +t*64

#pragma unroll 1
    for (int ph = 0; ph < 2; ++ph) {
        const int qt = ph ? 15 - ip : ip;  // 128-row q-tile index
        const int npair = qt + 1;          // kt pairs (nk = 2*qt+2, always even)
        const int qbase = qt * 128 + ws * 32;

        // Q B-frags: lane: q-col = qbase+col, dk = dkc*16 + hi*8 + j
        const __bf16* qr = Qb + (size_t)(qbase + col) * 2048;
        bf16x8 qf[4];
#pragma unroll
        for (int dkc = 0; dkc < 4; ++dkc)
            qf[dkc] = *(const bf16x8*)(qr + dkc * 16 + hi * 8);

        floatx4 lacc = {};
        f32x16 oa[2] = {};

        // stage pair p (K tiles 2p,2p+1 + V tiles 2p,2p+1) into dbuf slot
        auto stage = [&](int p, int sbuf) {
            const __bf16* kg = kgB + (size_t)(2 * p) * 64 * 2048;
            const __bf16* vg = vgB + 2 * p * 64;
            __bf16* kd = &Ks[sbuf][0][tid * 8];
            __bf16* vd = &Vts[sbuf][0][tid * 8];
            gl_lds16(kg, kd);
            gl_lds16(kg + (size_t)64 * 2048, kd + 4096);
            gl_lds16(vg, vd);
            gl_lds16(vg + 64, vd + 4096);
        };

        stage(0, 0);
        if (npair > 1) stage(1, 1);

        for (int kp = 0; kp < npair; ++kp) {
            const int buf = kp & 1;
            if (kp + 1 < npair) {
                asm volatile("s_waitcnt vmcnt(4)" ::: "memory");
            } else {
                asm volatile("s_waitcnt vmcnt(0)" ::: "memory");
            }
            __builtin_amdgcn_sched_barrier(0);
            __builtin_amdgcn_s_barrier();

            const int kt = 2 * kp + g;
            const int kbase = kt * 64;
            if (kbase <= qbase + 31) {     // else: whole wave fully masked
                const __bf16* ks = Ks[buf][g];
                const __bf16* vs = Vts[buf][g];

                // --- S^T = K.Q^T : acc[kt2] covers k rows kt2*32+{C rows} ---
                f32x16 acc[2] = {};
                __builtin_amdgcn_s_setprio(1);
#pragma unroll
                for (int kt2 = 0; kt2 < 2; ++kt2)
#pragma unroll
                    for (int dkc = 0; dkc < 4; ++dkc) {
                        const bf16x8 kb = *(const bf16x8*)(ks + off[kt2][dkc]);
                        acc[kt2] = __builtin_amdgcn_mfma_f32_32x32x16_bf16(
                            kb, qf[dkc], acc[kt2], 0, 0, 0);
                    }
                __builtin_amdgcn_s_setprio(0);

                // --- causal mask (only the last pair can touch the diagonal) ---
                if (kp == npair - 1) {
#pragma unroll
                    for (int kt2 = 0; kt2 < 2; ++kt2)
#pragma unroll
                        for (int reg = 0; reg < 16; ++reg) {
                            const int kloc = kt2 * 32 + (reg & 3) + 8 * (reg >> 2) + 4 * hi;
                            if (kbase + kloc > qbase + col) acc[kt2][reg] = NEG;
                        }
                }
                // --- fixed-ref softmax: p = exp2(s); per-lane partial l ---
#pragma unroll
                for (int kt2 = 0; kt2 < 2; ++kt2)
#pragma unroll
                    for (int reg = 0; reg < 16; ++reg) {
                        const float p = __builtin_exp2f(acc[kt2][reg]);
                        acc[kt2][reg] = p;
                        lacc[reg & 3] += p;
                    }

                // --- pack P^T B-frags: cross-half exchange via shfl_xor 32 ---
                // frag[tc] j<4 from lo-half regs R..R+3, j>=4 from hi-half
                // same regs, R = 8*(tc&1) + 4*hi(target).
                bf16x8 pf[4];
#pragma unroll
                for (int tc = 0; tc < 4; ++tc) {
                    const int kt2 = tc >> 1, c16 = (tc & 1) * 8;
                    const unsigned int a0 = pkbf(acc[kt2][c16 + 0], acc[kt2][c16 + 1]);
                    const unsigned int a1 = pkbf(acc[kt2][c16 + 2], acc[kt2][c16 + 3]);
                    const unsigned int b0 = pkbf(acc[kt2][c16 + 4], acc[kt2][c16 + 5]);
                    const unsigned int b1 = pkbf(acc[kt2][c16 + 6], acc[kt2][c16 + 7]);
                    const unsigned int s0 = hi ? a0 : b0, s1 = hi ? a1 : b1;
                    const unsigned int r0 = __shfl_xor(s0, 32);
                    const unsigned int r1 = __shfl_xor(s1, 32);
                    uint4v dv;
                    dv[0] = hi ? r0 : a0; dv[1] = hi ? r1 : a1;
                    dv[2] = hi ? b0 : r0; dv[3] = hi ? b1 : r1;
                    pf[tc] = __builtin_bit_cast(bf16x8, dv);
                }

                // --- O^T += V^T.P^T (plain V layout: frag = single b128) ---
                __builtin_amdgcn_s_setprio(1);
#pragma unroll
                for (int dt = 0; dt < 2; ++dt)
#pragma unroll
                    for (int tc = 0; tc < 4; ++tc) {
                        const bf16x8 vf = *(const bf16x8*)(vs + off[dt][tc]);
                        oa[dt] = __builtin_amdgcn_mfma_f32_32x32x16_bf16(
                            vf, pf[tc], oa[dt], 0, 0, 0);
                    }
                __builtin_amdgcn_s_setprio(0);
            }
            __builtin_amdgcn_sched_barrier(0);
            __builtin_amdgcn_s_barrier();   // all reads of buf done
            if (kp + 2 < npair) stage(kp + 2, buf);
        }

        // --- cross-group combine (linear: fixed-ref softmax) via LDS scratch ---
        __syncthreads();  // compiler-visible fence before LDS reuse as scratch
        float lt = lacc[0] + lacc[1] + lacc[2] + lacc[3];
        lt += __shfl_xor(lt, 32);          // combine lane halves (same q-col)
        float* sco = (float*)&Ks[0][0][0]; // 8 slots x 4 waves x 256 f32 = 32 KB
        float* scl = (float*)&Vts[0][0][0];
        if (g == 1) {
#pragma unroll
            for (int dt = 0; dt < 2; ++dt)
#pragma unroll
                for (int a = 0; a < 4; ++a) {
                    floatx4 t4;
                    t4[0] = oa[dt][4 * a + 0]; t4[1] = oa[dt][4 * a + 1];
                    t4[2] = oa[dt][4 * a + 2]; t4[3] = oa[dt][4 * a + 3];
                    *(floatx4*)(sco + (dt * 4 + a) * 1024 + ws * 256 + lane * 4) = t4;
                }
            scl[ws * 64 + lane] = lt;
        }
        __syncthreads();
        if (g == 0) {
#pragma unroll
            for (int dt = 0; dt < 2; ++dt)
#pragma unroll
                for (int a = 0; a < 4; ++a) {
                    const floatx4 t4 =
                        *(const floatx4*)(sco + (dt * 4 + a) * 1024 + ws * 256 + lane * 4);
                    oa[dt][4 * a + 0] += t4[0]; oa[dt][4 * a + 1] += t4[1];
                    oa[dt][4 * a + 2] += t4[2]; oa[dt][4 * a + 3] += t4[3];
                }
            lt += scl[ws * 64 + lane];
            const float inv = 1.f / lt;
            // lane: q = qbase+col; d = dt*32 + a*8 + hi*4 + r
            __bf16* cp = ctx + (size_t)(b * Tc + qbase + col) * 1024 + h * 64 + hi * 4;
#pragma unroll
            for (int dt = 0; dt < 2; ++dt)
#pragma unroll
                for (int a = 0; a < 4; ++a) {
                    bf16x4 rv;
#pragma unroll
                    for (int r = 0; r < 4; ++r)
                        rv[r] = (__bf16)(oa[dt][4 * a + r] * inv);
                    *(bf16x4*)(cp + dt * 32 + a * 8) = rv;
                }
        }
        __syncthreads();  // scratch/LDS reuse by next phase's staging
    }
}

// ---------------------------------------------------------------------------
// kernel_launch. Workspace (bf16 el): xb/ctxb (aliased) 4M | Wqkv 3M |
// Wot 1M | QKb 8M | Vt 4M = 20M el = 40 MB.
// ---------------------------------------------------------------------------
extern "C" void kernel_launch(void* const* d_in, const int* in_sizes, int n_in,
                              void* d_out, int out_size, void* d_ws, size_t ws_size,
                              hipStream_t stream) {
    const float* x  = (const float*)d_in[0];
    const float* Wq = (const float*)d_in[1];
    const float* bq = (const float*)d_in[2];
    const float* Wk = (const float*)d_in[3];
    const float* bk = (const float*)d_in[4];
    const float* Wv = (const float*)d_in[5];
    const float* bv = (const float*)d_in[6];
    const float* Wo = (const float*)d_in[7];
    const float* bo = (const float*)d_in[8];

    __bf16* xb   = (__bf16*)d_ws;                    // [4096][1024]
    __bf16* Wqkv = xb + (size_t)Mc * 1024;           // [3072][1024] (B^T)
    __bf16* Wot  = Wqkv + (size_t)3072 * 1024;       // [1024][1024] (B^T)
    __bf16* QKb  = Wot + (size_t)1024 * 1024;        // [4096][2048]  Q|K
    __bf16* Vtw  = QKb + (size_t)Mc * 2048;          // [32][64][2048] (plain d-major)
    __bf16* ctxb = xb;                               // alias: xb dead after QKV GEMM

    prep_all<<<dim3(16, 16, 8), 256, 0, stream>>>(x, Wq, Wk, Wv, Wo,
                                                  xb, Wqkv, Wot);

    // QKV projection: N=3072; Q pre-scaled; V streams into Vtw (plain)
    gemm_bt<128, true, true><<<dim3(24, 32), 256, 0, stream>>>(
        xb, Wqkv, bq, bk, bv, QKb, Vtw, 1024, 2048);

    attn_mfma<<<dim3(256), 512, 0, stream>>>(QKb, Vtw, ctxb);

    // Output projection: N=1024, fp32 out
    gemm_bt<64, false, false><<<dim3(16, 32), 256, 0, stream>>>(
        ctxb, Wot, bo, bo, bo, d_out, nullptr, 1024, 1024);
}

// Round 4
// 179.228 us; speedup vs baseline: 1.0776x; 1.0776x over previous
//
#include <hip/hip_runtime.h>
#include <hip/hip_bf16.h>

// Problem constants: B=2, T=2048, D=1024, H=16, DK=64
constexpr int Bc = 2;
constexpr int Tc = 2048;
constexpr int Mc = Bc * Tc;  // 4096
constexpr float CfQ = 0.18033688011112042f;  // (1/sqrt(64)) * log2(e)

typedef __attribute__((ext_vector_type(8))) __bf16 bf16x8;
typedef __attribute__((ext_vector_type(4))) __bf16 bf16x4;
typedef __attribute__((ext_vector_type(4))) float floatx4;

__device__ __forceinline__ void gl_lds16(const void* g, void* l) {
    __builtin_amdgcn_global_load_lds(
        (const __attribute__((address_space(1))) void*)g,
        (__attribute__((address_space(3))) void*)l, 16, 0, 0);
}

// ---------------------------------------------------------------------------
// Prep: z<4 -> weight transpose+convert; z>=4 -> x fp32->bf16 convert slices.
// ---------------------------------------------------------------------------
__global__ __launch_bounds__(256) void prep_all(const float* __restrict__ x,
                                                const float* __restrict__ Wq,
                                                const float* __restrict__ Wk,
                                                const float* __restrict__ Wv,
                                                const float* __restrict__ Wo,
                                                __bf16* __restrict__ xb,
                                                __bf16* __restrict__ Wqkv,
                                                __bf16* __restrict__ Wot) {
    const int z = blockIdx.z;
    const int tid = threadIdx.x;
    if (z >= 4) {
        const int lb = blockIdx.y * 16 + blockIdx.x;
        const size_t base = ((size_t)(z - 4) * 256 + lb) * 4096;
#pragma unroll
        for (int it = 0; it < 4; ++it) {
            const size_t i = base + (size_t)(it * 256 + tid) * 4;
            const float4 v = *(const float4*)(x + i);
            bf16x4 r;
            r[0] = (__bf16)v.x; r[1] = (__bf16)v.y;
            r[2] = (__bf16)v.z; r[3] = (__bf16)v.w;
            *(bf16x4*)(xb + i) = r;
        }
        return;
    }
    __shared__ float t[64][65];
    const float* W = (z == 0) ? Wq : (z == 1) ? Wk : (z == 2) ? Wv : Wo;
    __bf16* Wt = (z < 3) ? Wqkv + (size_t)z * 1024 * 1024 : Wot;
    const int k0 = blockIdx.y * 64, n0 = blockIdx.x * 64;
    const int c = tid & 63, r0 = tid >> 6;
#pragma unroll
    for (int i = 0; i < 16; ++i)
        t[r0 + i * 4][c] = W[(size_t)(k0 + r0 + i * 4) * 1024 + n0 + c];
    __syncthreads();
#pragma unroll
    for (int i = 0; i < 16; ++i) {
        const int r = r0 + i * 4;
        Wt[(size_t)(n0 + r) * 1024 + k0 + c] = (__bf16)t[c][r];
    }
}

// ---------------------------------------------------------------------------
// bf16 MFMA GEMM, BK=32, COUNTED-VMCNT DOUBLE-BUFFERED pipeline (same proven
// pattern as the attn k-loop): prologue stages steps 0,1; steady state waits
// vmcnt(L) (L = loads/step/thread) leaving the NEXT step's loads in flight
// across both barriers; re-stage into the just-freed buffer after barrier 2.
// LDS stays 32 KB (TN=128) -> occupancy unchanged vs the old drain loop.
// Swizzle for 32-el (64 B) rows: phys chunk = logical ^ ((row>>1)&3), applied
// to BOTH the staging global source and the frag read (uniform 8 lanes/slot
// -> conflict-free b128).
// FUSE_VT (QKV gemm): cols <1024 (Q) pre-scaled by CfQ; cols >=2048 (V)
// stream into Vp[bh][d][t-tile][t' perm] where t'=q*16+a*4+s for
// t=16a+4q+s — makes attention PV fragments single-b128 reads.
// ---------------------------------------------------------------------------
template <int TN, bool BF16_OUT, bool FUSE_VT>
__global__ __launch_bounds__(256) void gemm_bt(const __bf16* __restrict__ A,
                                               const __bf16* __restrict__ Bt,
                                               const float* __restrict__ b0,
                                               const float* __restrict__ b1,
                                               const float* __restrict__ b2,
                                               void* __restrict__ Cv,
                                               __bf16* __restrict__ Vt,
                                               int K, int ldc) {
    constexpr int NI = TN / 32;
    constexpr int NB = TN / 64;            // B-chunks per thread per K-step
    __shared__ __bf16 As[2][128 * 32];
    __shared__ __bf16 Bs[2][TN * 32];
    const int tid = threadIdx.x, lane = tid & 63, wave = tid >> 6;
    const int wm = wave & 1, wn = wave >> 1;
    const int bm = blockIdx.y * 128, bn = blockIdx.x * TN;
    const __bf16* Ab = A + (size_t)bm * K;
    const __bf16* Bb = Bt + (size_t)bn * K;
    const int quad = lane >> 4, tm = lane & 15;
    const int xsw = (tm >> 1) & 3;         // frag-read chunk swizzle

    floatx4 acc[4][NI] = {};

    // stage K-step (k0 = ks*32) into dbuf slot sbuf
    auto stage = [&](int k0, int sbuf) {
#pragma unroll
        for (int i = 0; i < 2; ++i) {      // A: 128x32 = 512 chunks / 256 thr
            const int s = i * 256 + tid;
            const int row = s >> 2;
            const int lc = (s & 3) ^ ((row >> 1) & 3);
            gl_lds16(Ab + (size_t)row * K + k0 + lc * 8, &As[sbuf][s * 8]);
        }
#pragma unroll
        for (int i = 0; i < NB; ++i) {     // B: TN x 32 chunks
            const int s = i * 256 + tid;
            const int row = s >> 2;
            const int lc = (s & 3) ^ ((row >> 1) & 3);
            gl_lds16(Bb + (size_t)row * K + k0 + lc * 8, &Bs[sbuf][s * 8]);
        }
    };

    const int nstep = K >> 5;
    stage(0, 0);
    stage(32, 1);

    for (int ks = 0; ks < nstep; ++ks) {
        const int buf = ks & 1;
        if (ks + 1 < nstep) {
            // wait for CURRENT step's loads only; next step's stay in flight
            if constexpr (TN == 128)
                asm volatile("s_waitcnt vmcnt(4)" ::: "memory");
            else
                asm volatile("s_waitcnt vmcnt(3)" ::: "memory");
        } else {
            asm volatile("s_waitcnt vmcnt(0)" ::: "memory");
        }
        __builtin_amdgcn_sched_barrier(0);
        __builtin_amdgcn_s_barrier();

        bf16x8 af[4], bfv[NI];
#pragma unroll
        for (int mi = 0; mi < 4; ++mi)
            af[mi] = *(const bf16x8*)(&As[buf][(wm * 64 + mi * 16 + tm) * 32 +
                                               ((quad ^ xsw) * 8)]);
#pragma unroll
        for (int ni = 0; ni < NI; ++ni)
            bfv[ni] = *(const bf16x8*)(&Bs[buf][(wn * (TN / 2) + ni * 16 + tm) * 32 +
                                                ((quad ^ xsw) * 8)]);
        __builtin_amdgcn_s_setprio(1);
#pragma unroll
        for (int mi = 0; mi < 4; ++mi)
#pragma unroll
            for (int ni = 0; ni < NI; ++ni)
                acc[mi][ni] = __builtin_amdgcn_mfma_f32_16x16x32_bf16(
                    af[mi], bfv[ni], acc[mi][ni], 0, 0, 0);
        __builtin_amdgcn_s_setprio(0);
        __builtin_amdgcn_sched_barrier(0);
        __builtin_amdgcn_s_barrier();      // all reads of buf done
        if (ks + 2 < nstep) stage((ks + 2) * 32, buf);
    }

#pragma unroll
    for (int ni = 0; ni < NI; ++ni) {
        const int gc = bn + wn * (TN / 2) + ni * 16 + tm;
        const float bias = (gc < 1024) ? b0[gc]
                         : (gc < 2048) ? b1[gc - 1024]
                                       : b2[gc - 2048];
        const float scale = (FUSE_VT && gc < 1024) ? CfQ : 1.0f;
#pragma unroll
        for (int mi = 0; mi < 4; ++mi) {
            const int gr0 = bm + wm * 64 + mi * 16 + quad * 4;
            if (FUSE_VT && gc >= 2048) {
                bf16x4 pv;
#pragma unroll
                for (int r = 0; r < 4; ++r) pv[r] = (__bf16)(acc[mi][ni][r] + bias);
                const int bb = gr0 >> 11, tloc = gr0 & 2047;
                const int hh = (gc - 2048) >> 6, dd = gc & 63;
                // permuted within 64-tile: t' = ((t>>2)&3)*16 + ((t>>4)&3)*4 + (t&3)
                const int tperm = (tloc & ~63) + ((tloc >> 2) & 3) * 16 +
                                  ((tloc >> 4) & 3) * 4;
                *(bf16x4*)(Vt + ((size_t)(bb * 16 + hh) * 64 + dd) * 2048 + tperm) = pv;
            } else if (BF16_OUT) {
#pragma unroll
                for (int r = 0; r < 4; ++r)
                    ((__bf16*)Cv)[(size_t)(gr0 + r) * ldc + gc] =
                        (__bf16)((acc[mi][ni][r] + bias) * scale);
            } else {
#pragma unroll
                for (int r = 0; r < 4; ++r)
                    ((float*)Cv)[(size_t)(gr0 + r) * ldc + gc] =
                        acc[mi][ni][r] + bias;
            }
        }
    }
}

// ---------------------------------------------------------------------------
// MFMA flash attention (causal), S^T formulation, fixed-reference softmax.
// (R2 version — proven ~41.5 us.) Grid: 512 one-dim blocks of 512 threads
// (8 waves), 2 blocks/CU. XCD-clustered remap: XCD x hosts only bh in
// {4x..4x+3} -> per-XCD K/V working set ~2.5 MB < 4 MB L2.
// Block handles q-tile pair (ip, 31-ip): 33 kt total, uniform duration.
// Two 4-wave groups split k-range even/odd; partial O,l combine linearly.
// Counted-vmcnt pipeline: prefetch depth 2 tile-pairs, steady-state wait
// vmcnt(4); never drain to 0 in the loop.
// Q pre-scaled by CfQ in the GEMM -> p = exp2(s) directly.
// V in permuted Vp layout -> PV A-frag = single swizzled ds_read_b128.
// ---------------------------------------------------------------------------
__global__ __launch_bounds__(512, 4) void attn_mfma(const __bf16* __restrict__ QK,
                                                    const __bf16* __restrict__ Vt,
                                                    __bf16* __restrict__ ctx) {
    constexpr float NEG = -1e30f;

    __shared__ __bf16 Ks[2][2][64 * 64];   // [dbuf][group][tile]
    __shared__ __bf16 Vts[2][2][64 * 64];

    const int tid = threadIdx.x, lane = tid & 63, w = tid >> 6;
    const int g = w >> 2, wq = w & 3;      // k-group, wave-in-group
    const int c = lane & 15, quad = lane >> 4;
    const int n = blockIdx.x;
    const int bh = (n & 7) * 4 + ((n >> 3) & 3);
    const int ip = n >> 5;                 // pair index: q-tiles (ip, 31-ip)
    const int b = bh >> 4, h = bh & 15;

    const __bf16* Qb = QK + (size_t)(b * Tc) * 2048 + h * 64;
    const __bf16* Kb = Qb + 1024;
    const __bf16* Vtb = Vt + (size_t)bh * 64 * 2048;

    // --- hoisted frag LDS offsets (sw = c&7 loop-invariant) ---
    const int sw = c & 7;
    int koff0[4], koff1[4];
#pragma unroll
    for (int ni = 0; ni < 4; ++ni) {
        const int krow = ni * 16 + c;
        koff0[ni] = krow * 64 + (quad ^ sw) * 8;
        koff1[ni] = krow * 64 + ((4 + quad) ^ sw) * 8;
    }
    int voff[4][2];
#pragma unroll
    for (int di = 0; di < 4; ++di) {
        const int vrow = di * 16 + c;
#pragma unroll
        for (int pr = 0; pr < 2; ++pr)
            voff[di][pr] = vrow * 64 + ((quad * 2 + pr) ^ sw) * 8;
    }

    // --- staging addresses: 512 threads, 1 chunk (16B) per tile per thread ---
    const int srow = tid >> 3;                       // 0..63
    const int slc = (tid & 7) ^ (srow & 7);          // swizzled chunk
    const __bf16* kgB = Kb + (size_t)srow * 2048 + slc * 8;   // K tile t: +t*64*2048
    const __bf16* vgB = Vtb + (size_t)srow * 2048 + slc * 8;  // V tile t: +t*64

#pragma unroll 1
    for (int ph = 0; ph < 2; ++ph) {
        const int qt = ph ? 31 - ip : ip;
        const int nk = qt + 1;
        const int npair = (nk + 1) >> 1;   // staged tiles 2*kp, 2*kp+1 (<=31 always)

        // Q fragments (B-operand: n = q-row = lane&15); both groups same q-rows
        const __bf16* qr = Qb + (size_t)(qt * 64 + wq * 16 + c) * 2048;
        const bf16x8 qf0 = *(const bf16x8*)(qr + quad * 8);
        const bf16x8 qf1 = *(const bf16x8*)(qr + 32 + quad * 8);

        floatx4 lacc = {};
        floatx4 oa[4] = {};

        // stage pair p (K tiles 2p,2p+1 + V tiles 2p,2p+1) into dbuf slot
        auto stage = [&](int p, int sbuf) {
            const __bf16* kg = kgB + (size_t)(2 * p) * 64 * 2048;
            const __bf16* vg = vgB + 2 * p * 64;
            __bf16* kd = &Ks[sbuf][0][tid * 8];
            __bf16* vd = &Vts[sbuf][0][tid * 8];
            gl_lds16(kg, kd);
            gl_lds16(kg + (size_t)64 * 2048, kd + 4096);
            gl_lds16(vg, vd);
            gl_lds16(vg + 64, vd + 4096);
        };

        // prologue: prefetch depth 2 (4 loads per pair per thread)
        stage(0, 0);
        if (npair > 1) stage(1, 1);

        for (int kp = 0; kp < npair; ++kp) {
            const int buf = kp & 1;
            // wait for CURRENT buffer's 4 loads only; keep next pair's 4 in flight
            if (kp + 1 < npair) {
                asm volatile("s_waitcnt vmcnt(4)" ::: "memory");
            } else {
                asm volatile("s_waitcnt vmcnt(0)" ::: "memory");
            }
            __builtin_amdgcn_sched_barrier(0);
            __builtin_amdgcn_s_barrier();

            const int kt = 2 * kp + g;
            if (kt < nk) {
                const __bf16* ks = Ks[buf][g];
                const __bf16* vs = Vts[buf][g];

                // --- S^T = K.Q^T : sv[ni][r] = S[k=16ni+quad*4+r][q=c] ---
                float sv[4][4];
                __builtin_amdgcn_s_setprio(1);
#pragma unroll
                for (int ni = 0; ni < 4; ++ni) {
                    const bf16x8 kb0 = *(const bf16x8*)(ks + koff0[ni]);
                    const bf16x8 kb1 = *(const bf16x8*)(ks + koff1[ni]);
                    floatx4 a = {};
                    a = __builtin_amdgcn_mfma_f32_16x16x32_bf16(kb0, qf0, a, 0, 0, 0);
                    a = __builtin_amdgcn_mfma_f32_16x16x32_bf16(kb1, qf1, a, 0, 0, 0);
#pragma unroll
                    for (int r = 0; r < 4; ++r) sv[ni][r] = a[r];
                }
                __builtin_amdgcn_s_setprio(0);

                // --- fixed-m softmax: p = exp2(s); per-lane partial l ---
                if (kt == qt) {  // diagonal: mask k_loc > q_loc
#pragma unroll
                    for (int ni = 0; ni < 4; ++ni)
#pragma unroll
                        for (int r = 0; r < 4; ++r)
                            if (ni * 16 + quad * 4 + r > wq * 16 + c) sv[ni][r] = NEG;
                }
#pragma unroll
                for (int ni = 0; ni < 4; ++ni) {
#pragma unroll
                    for (int r = 0; r < 4; ++r) sv[ni][r] = __builtin_exp2f(sv[ni][r]);
                    lacc[0] += sv[ni][0];
                    lacc[1] += sv[ni][1];
                    lacc[2] += sv[ni][2];
                    lacc[3] += sv[ni][3];
                }

                // pack P into B-frags (slot quad*8+j <-> t = 16*(2pr+(j>=4)) + quad*4+(j&3))
                bf16x8 pb[2];
#pragma unroll
                for (int pr = 0; pr < 2; ++pr)
#pragma unroll
                    for (int j = 0; j < 4; ++j) {
                        pb[pr][j] = (__bf16)sv[pr * 2][j];
                        pb[pr][4 + j] = (__bf16)sv[pr * 2 + 1][j];
                    }

                // --- O^T += V^T.P^T (Vp layout: frag = single b128 read) ---
                __builtin_amdgcn_s_setprio(1);
#pragma unroll
                for (int di = 0; di < 4; ++di) {
#pragma unroll
                    for (int pr = 0; pr < 2; ++pr) {
                        const bf16x8 vf = *(const bf16x8*)(vs + voff[di][pr]);
                        oa[di] = __builtin_amdgcn_mfma_f32_16x16x32_bf16(
                            vf, pb[pr], oa[di], 0, 0, 0);
                    }
                }
                __builtin_amdgcn_s_setprio(0);
            }
            __builtin_amdgcn_sched_barrier(0);
            __builtin_amdgcn_s_barrier();   // all reads of buf done
            if (kp + 2 < npair) stage(kp + 2, buf);
        }

        // --- cross-group combine (linear: fixed-ref softmax) via LDS scratch ---
        __syncthreads();  // compiler-visible fence before LDS reuse as scratch
        float lsum = lacc[0] + lacc[1] + lacc[2] + lacc[3];
        float* sc = (float*)&Ks[0][0][0];  // 4 waves x 1088 floats = 17 KB < 32 KB
        if (g == 1) {
#pragma unroll
            for (int di = 0; di < 4; ++di)
                *(floatx4*)(sc + wq * 1088 + di * 256 + lane * 4) = oa[di];
            sc[wq * 1088 + 1024 + lane] = lsum;
        }
        __syncthreads();
        if (g == 0) {
#pragma unroll
            for (int di = 0; di < 4; ++di)
                oa[di] += *(const floatx4*)(sc + wq * 1088 + di * 256 + lane * 4);
            lsum += sc[wq * 1088 + 1024 + lane];
            lsum += __shfl_xor(lsum, 16);
            lsum += __shfl_xor(lsum, 32);
            const float inv = 1.f / lsum;
            __bf16* cp = ctx + (size_t)(b * Tc + qt * 64 + wq * 16 + c) * 1024 +
                         h * 64 + quad * 4;
#pragma unroll
            for (int di = 0; di < 4; ++di) {
                bf16x4 rv;
#pragma unroll
                for (int r = 0; r < 4; ++r) rv[r] = (__bf16)(oa[di][r] * inv);
                *(bf16x4*)(cp + di * 16) = rv;
            }
        }
        __syncthreads();  // scratch/LDS reuse by next phase's staging
    }
}

// ---------------------------------------------------------------------------
// kernel_launch. Workspace (bf16 el): xb/ctxb (aliased) 4M | Wqkv 3M |
// Wot 1M | QKb 8M | Vt 4M = 20M el = 40 MB.
// ---------------------------------------------------------------------------
extern "C" void kernel_launch(void* const* d_in, const int* in_sizes, int n_in,
                              void* d_out, int out_size, void* d_ws, size_t ws_size,
                              hipStream_t stream) {
    const float* x  = (const float*)d_in[0];
    const float* Wq = (const float*)d_in[1];
    const float* bq = (const float*)d_in[2];
    const float* Wk = (const float*)d_in[3];
    const float* bk = (const float*)d_in[4];
    const float* Wv = (const float*)d_in[5];
    const float* bv = (const float*)d_in[6];
    const float* Wo = (const float*)d_in[7];
    const float* bo = (const float*)d_in[8];

    __bf16* xb   = (__bf16*)d_ws;                    // [4096][1024]
    __bf16* Wqkv = xb + (size_t)Mc * 1024;           // [3072][1024] (B^T)
    __bf16* Wot  = Wqkv + (size_t)3072 * 1024;       // [1024][1024] (B^T)
    __bf16* QKb  = Wot + (size_t)1024 * 1024;        // [4096][2048]  Q|K
    __bf16* Vtw  = QKb + (size_t)Mc * 2048;          // [32][64][2048] (permuted)
    __bf16* ctxb = xb;                               // alias: xb dead after QKV GEMM

    prep_all<<<dim3(16, 16, 8), 256, 0, stream>>>(x, Wq, Wk, Wv, Wo,
                                                  xb, Wqkv, Wot);

    // QKV projection: N=3072; Q pre-scaled; V streams permuted into Vtw
    gemm_bt<128, true, true><<<dim3(24, 32), 256, 0, stream>>>(
        xb, Wqkv, bq, bk, bv, QKb, Vtw, 1024, 2048);

    attn_mfma<<<dim3(512), 512, 0, stream>>>(QKb, Vtw, ctxb);

    // Output projection: N=1024, fp32 out
    gemm_bt<64, false, false><<<dim3(16, 32), 256, 0, stream>>>(
        ctxb, Wot, bo, bo, bo, d_out, nullptr, 1024, 1024);
}